// Round 2
// baseline (181.055 us; speedup 1.0000x reference)
//
#include <hip/hip_runtime.h>
#include <math.h>

#define BATCH 128
#define NNODE 512
#define RU 64
#define IN_PER_NODE 2
#define MEM_DIM 16
#define BOT_DIM 4
#define IN_SZ 66            // IN_PER_NODE + RU
#define OUT_SZ 256          // 4*RU
#define HID (NNODE*RU)      // 32768
#define W3_ROW 16896        // IN_SZ*OUT_SZ
#define KPAD 96             // K padded to 3 x 32 for MFMA
#define KSTRIDE 104         // LDS row stride in bf16 (52 dwords -> 2-way max aliasing)

typedef __attribute__((ext_vector_type(8))) short short8;
typedef __attribute__((ext_vector_type(4))) float float4v;

__device__ __forceinline__ unsigned short f2bf(float f) {
    unsigned int u = __float_as_uint(f);
    unsigned int r = (u + 0x7FFFu + ((u >> 16) & 1u)) >> 16;
    return (unsigned short)r;
}

__device__ __forceinline__ float fsig(float x) {
    return __builtin_amdgcn_rcpf(1.0f + __expf(-x));
}
__device__ __forceinline__ float ftanh(float x) {
    return 1.0f - 2.0f * __builtin_amdgcn_rcpf(1.0f + __expf(2.0f * x));
}

__global__ __launch_bounds__(256) void dlstm_kernel(
    const float* __restrict__ inputs, const float* __restrict__ hx,
    const float* __restrict__ cx,     const float* __restrict__ memory,
    const float* __restrict__ w1,     const float* __restrict__ b1,
    const float* __restrict__ w2,     const float* __restrict__ b2,
    const float* __restrict__ w3,     const float* __restrict__ b3,
    const float* __restrict__ b_out,  float* __restrict__ out)
{
    // xs: [batch][k] row-major bf16; Wl: [col][k] column-major bf16
    __shared__ alignas(16) unsigned short xs[BATCH][KSTRIDE];   // 26624 B
    __shared__ alignas(16) unsigned short Wl[128][KSTRIDE];     // 26624 B
    __shared__ float mem1[MEM_DIM];
    __shared__ float mem2[BOT_DIM];

    const int tid = threadIdx.x;
    const int n   = blockIdx.x >> 1;          // node
    const int r0  = (blockIdx.x & 1) * 32;    // which half of RU

    // ---- stage xs = concat(input, h, zeros) for this node, all batches ----
    for (int e = tid; e < BATCH * KPAD; e += 256) {
        int b = e / KPAD;
        int i = e - b * KPAD;
        float v = 0.f;
        if (i < IN_PER_NODE)
            v = inputs[b * (NNODE * IN_PER_NODE) + n * IN_PER_NODE + i];
        else if (i < IN_SZ)
            v = hx[(size_t)b * HID + n * RU + (i - IN_PER_NODE)];
        xs[b][i] = f2bf(v);
    }

    // ---- hypernetwork bottleneck ----
    if (tid < MEM_DIM) {
        float s = b1[tid];
        #pragma unroll
        for (int j = 0; j < MEM_DIM; ++j)
            s += memory[n * MEM_DIM + j] * w1[j * MEM_DIM + tid];
        mem1[tid] = ftanh(s);
    }
    __syncthreads();
    if (tid < BOT_DIM) {
        float s = b2[tid];
        #pragma unroll
        for (int j = 0; j < MEM_DIM; ++j)
            s += mem1[j] * w2[j * BOT_DIM + tid];
        mem2[tid] = ftanh(s);
    }
    __syncthreads();
    const float m0 = mem2[0], m1 = mem2[1], m2 = mem2[2], m3 = mem2[3];

    // ---- materialize W columns, col-major bf16.
    // col c -> o = g*64 + r0 + rh*16 + q, where q=c&15, ct=c>>4, g=ct&3, rh=ct>>2
    for (int e = tid; e < KPAD * 128; e += 256) {
        int i = e >> 7;       // k row
        int c = e & 127;      // col
        unsigned short v = 0;
        if (i < IN_SZ) {
            int q  = c & 15;
            int ct = c >> 4;
            int o  = (ct & 3) * 64 + r0 + (ct >> 2) * 16 + q;
            int j  = i * OUT_SZ + o;
            float f = b3[j] + m0 * w3[j] + m1 * w3[W3_ROW + j]
                            + m2 * w3[2 * W3_ROW + j] + m3 * w3[3 * W3_ROW + j];
            v = f2bf(f);
        }
        Wl[c][i] = v;
    }
    __syncthreads();

    // ---- MFMA main loop: wave w owns batch rows [w*32, w*32+32), all 128 cols ----
    const int w    = tid >> 6;
    const int lane = tid & 63;
    const int q    = lane & 15;
    const int quad = lane >> 4;

    float4v acc[2][8];
    #pragma unroll
    for (int rt = 0; rt < 2; ++rt)
        #pragma unroll
        for (int ct = 0; ct < 8; ++ct)
            acc[rt][ct] = (float4v){0.f, 0.f, 0.f, 0.f};

    #pragma unroll
    for (int kk = 0; kk < KPAD; kk += 32) {
        const int ko = kk + quad * 8;
        short8 a0 = *(const short8*)&xs[w * 32 + q][ko];
        short8 a1 = *(const short8*)&xs[w * 32 + 16 + q][ko];
        short8 bf[8];
        #pragma unroll
        for (int ct = 0; ct < 8; ++ct)
            bf[ct] = *(const short8*)&Wl[ct * 16 + q][ko];
        #pragma unroll
        for (int ct = 0; ct < 8; ++ct) {
            acc[0][ct] = __builtin_amdgcn_mfma_f32_16x16x32_bf16(a0, bf[ct], acc[0][ct], 0, 0, 0);
            acc[1][ct] = __builtin_amdgcn_mfma_f32_16x16x32_bf16(a1, bf[ct], acc[1][ct], 0, 0, 0);
        }
    }

    // ---- epilogue: lane holds all 4 gates for (b, rr=rh*16+q) in-register ----
    float bo[4][2];
    #pragma unroll
    for (int g = 0; g < 4; ++g)
        #pragma unroll
        for (int rh = 0; rh < 2; ++rh)
            bo[g][rh] = b_out[g * 64 + r0 + rh * 16 + q];

    #pragma unroll
    for (int rt = 0; rt < 2; ++rt) {
        #pragma unroll
        for (int v = 0; v < 4; ++v) {
            const int b = w * 32 + rt * 16 + quad * 4 + v;
            #pragma unroll
            for (int rh = 0; rh < 2; ++rh) {
                // reference: val = sigmoid(matmul) + b_out, THEN gate activations
                float vi = fsig(acc[rt][rh * 4 + 0][v]) + bo[0][rh];
                float vf = fsig(acc[rt][rh * 4 + 1][v]) + bo[1][rh];
                float vg = fsig(acc[rt][rh * 4 + 2][v]) + bo[2][rh];
                float vo = fsig(acc[rt][rh * 4 + 3][v]) + bo[3][rh];
                float it = fsig(vi);
                float ft = fsig(vf);
                float gt = ftanh(vg);
                float ot = fsig(vo);
                size_t idx = (size_t)b * HID + n * RU + r0 + rh * 16 + q;
                float c = cx[idx] * ft + it * gt;
                out[idx] = ot * ftanh(c);                 // hy
                out[(size_t)BATCH * HID + idx] = c;       // cy
            }
        }
    }
}

extern "C" void kernel_launch(void* const* d_in, const int* in_sizes, int n_in,
                              void* d_out, int out_size, void* d_ws, size_t ws_size,
                              hipStream_t stream) {
    const float* inputs = (const float*)d_in[0];
    const float* hx     = (const float*)d_in[1];
    const float* cx     = (const float*)d_in[2];
    const float* memory = (const float*)d_in[3];
    const float* w1     = (const float*)d_in[4];
    const float* b1     = (const float*)d_in[5];
    const float* w2     = (const float*)d_in[6];
    const float* b2     = (const float*)d_in[7];
    const float* w3     = (const float*)d_in[8];
    const float* b3     = (const float*)d_in[9];
    const float* b_out  = (const float*)d_in[10];
    float* out = (float*)d_out;

    dlstm_kernel<<<NNODE * 2, 256, 0, stream>>>(
        inputs, hx, cx, memory, w1, b1, w2, b2, w3, b3, b_out, out);
}

// Round 3
// 139.441 us; speedup vs baseline: 1.2984x; 1.2984x over previous
//
#include <hip/hip_runtime.h>
#include <math.h>

#define BATCH 128
#define NNODE 512
#define RU 64
#define MEM_DIM 16
#define BOT_DIM 4
#define IN_SZ 66
#define OUT_SZ 256
#define HID (NNODE*RU)          // 32768
#define W3_ROW 16896            // IN_SZ*OUT_SZ
#define COL_SHORTS 104          // 13 chunks x 8 bf16 per column (52 dwords -> 8 bank-starts, 2-way, free)
#define NODE_W_SHORTS (256*COL_SHORTS)   // 26624 shorts = 53248 B per node
#define HALF_W_SHORTS (128*COL_SHORTS)   // 13312 shorts = 26624 B per half

typedef __attribute__((ext_vector_type(8))) short short8;
typedef __attribute__((ext_vector_type(4))) float float4v;

__device__ __forceinline__ unsigned short f2bf(float f) {
    unsigned int u = __float_as_uint(f);
    unsigned int r = (u + 0x7FFFu + ((u >> 16) & 1u)) >> 16;
    return (unsigned short)r;
}
__device__ __forceinline__ float fsig(float x) {
    return __builtin_amdgcn_rcpf(1.0f + __expf(-x));
}
__device__ __forceinline__ float ftanh(float x) {
    return 1.0f - 2.0f * __builtin_amdgcn_rcpf(1.0f + __expf(2.0f * x));
}

// ---------------- Kernel 1: hypernet + W materialization ----------------
// Block = node. Thread c owns output column slot c (col o = colmap(c)).
// Slot layout per column (k-index): slots 0..63 = h rows (W rows 2..65),
// slots 64,65 = input rows (W rows 0,1), slots 66..103 = zero pad.
__global__ __launch_bounds__(256) void wgen_kernel(
    const float* __restrict__ memory, const float* __restrict__ w1,
    const float* __restrict__ b1,     const float* __restrict__ w2,
    const float* __restrict__ b2,     const float* __restrict__ w3,
    const float* __restrict__ b3,     unsigned short* __restrict__ W_ws)
{
    __shared__ unsigned short Wn[256][COL_SHORTS];   // 53248 B, final global layout
    const int c = threadIdx.x;
    const int n = blockIdx.x;

    // per-thread redundant hypernet (tiny; avoids barrier-fenced single-wave phases)
    float memv[MEM_DIM];
    #pragma unroll
    for (int j = 0; j < MEM_DIM; ++j) memv[j] = memory[n * MEM_DIM + j];
    float mem1[MEM_DIM];
    #pragma unroll
    for (int t = 0; t < MEM_DIM; ++t) {
        float s = b1[t];
        #pragma unroll
        for (int j = 0; j < MEM_DIM; ++j) s += memv[j] * w1[j * MEM_DIM + t];
        mem1[t] = ftanh(s);
    }
    float m[BOT_DIM];
    #pragma unroll
    for (int t = 0; t < BOT_DIM; ++t) {
        float s = b2[t];
        #pragma unroll
        for (int j = 0; j < MEM_DIM; ++j) s += mem1[j] * w2[j * BOT_DIM + t];
        m[t] = ftanh(s);
    }

    // col slot c -> output index o (gate-grouped so kernel-2 epilogue is in-register)
    const int ct = c >> 4, q = c & 15;
    const int o = (ct & 3) * 64 + (ct >> 2) * 16 + q;
    const float* p0 = w3 + o;   // rows at +r*W3_ROW, coalesced across threads (o consecutive per 16)
    const float* pb = b3 + o;

    for (int i = 0; i < IN_SZ; ++i) {
        int j = i * OUT_SZ;
        float f = pb[j] + m[0] * p0[j] + m[1] * p0[W3_ROW + j]
                        + m[2] * p0[2 * W3_ROW + j] + m[3] * p0[3 * W3_ROW + j];
        int s = (i < 2) ? (64 + i) : (i - 2);
        Wn[c][s] = f2bf(f);
    }
    #pragma unroll
    for (int s = IN_SZ; s < COL_SHORTS; ++s) Wn[c][s] = 0;
    __syncthreads();

    // write out column c: 13 contiguous 16B chunks; wave tiles a contiguous 13KB span
    unsigned short* dst = W_ws + (size_t)n * NODE_W_SHORTS + c * COL_SHORTS;
    #pragma unroll
    for (int kc = 0; kc < 13; ++kc)
        *(short8*)(dst + kc * 8) = *(const short8*)(&Wn[c][kc * 8]);
}

// ---------------- Kernel 2: MFMA GEMM + LSTM epilogue ----------------
// Block = (node, col-half). W half-tile DMA'd to LDS; A fragments straight
// from global (hx/inputs) into registers; one barrier; 48 MFMA/wave.
__global__ __launch_bounds__(256, 3) void gemm_kernel(
    const float* __restrict__ inputs, const float* __restrict__ hx,
    const float* __restrict__ cx,     const float* __restrict__ b_out,
    const unsigned short* __restrict__ W_ws, float* __restrict__ out)
{
    __shared__ unsigned short Wl[128][COL_SHORTS];   // 26624 B
    const int tid  = threadIdx.x;
    const int n    = (int)blockIdx.x >> 1;
    const int h    = (int)blockIdx.x & 1;
    const int w    = tid >> 6;
    const int lane = tid & 63;
    const int q    = lane & 15;
    const int quad = lane >> 4;

    // 1. async DMA W half-tile (straight copy, 26 x 1KB wave-insts)
    const unsigned short* gW = W_ws + (size_t)n * NODE_W_SHORTS + h * HALF_W_SHORTS;
    for (int t = w; t < 26; t += 4) {
        __builtin_amdgcn_global_load_lds(
            (__attribute__((address_space(1))) void*)(gW + t * 512 + lane * 8),
            (__attribute__((address_space(3))) void*)(&Wl[0][0] + t * 512),
            16, 0, 0);
    }

    // 2. A fragments from global while DMA is in flight
    short8 a[3][2];
    #pragma unroll
    for (int rt = 0; rt < 2; ++rt) {
        const int row = w * 32 + rt * 16 + q;
        const float* hrow = hx + (size_t)row * HID + n * RU + quad * 8;
        #pragma unroll
        for (int ks = 0; ks < 2; ++ks) {
            float4v f0 = *(const float4v*)(hrow + ks * 32);
            float4v f1 = *(const float4v*)(hrow + ks * 32 + 4);
            short8 t;
            t[0] = (short)f2bf(f0[0]); t[1] = (short)f2bf(f0[1]);
            t[2] = (short)f2bf(f0[2]); t[3] = (short)f2bf(f0[3]);
            t[4] = (short)f2bf(f1[0]); t[5] = (short)f2bf(f1[1]);
            t[6] = (short)f2bf(f1[2]); t[7] = (short)f2bf(f1[3]);
            a[ks][rt] = t;
        }
        short8 t2 = {0, 0, 0, 0, 0, 0, 0, 0};
        if (quad == 0) {   // k-slots 64,65 = this node's two raw inputs
            const float* ip = inputs + (size_t)row * (NNODE * IN_SZ - NNODE * RU) + n * 2;
            t2[0] = (short)f2bf(ip[0]);
            t2[1] = (short)f2bf(ip[1]);
        }
        a[2][rt] = t2;
    }

    float4v acc[2][8];
    #pragma unroll
    for (int rt = 0; rt < 2; ++rt)
        #pragma unroll
        for (int ctl = 0; ctl < 8; ++ctl)
            acc[rt][ctl] = (float4v){0.f, 0.f, 0.f, 0.f};

    __syncthreads();   // drains DMA (vmcnt(0)) + barrier

    // 3. K-loop: 3 ksteps x 8 col-frags x 2 row-frags
    #pragma unroll
    for (int ks = 0; ks < 3; ++ks) {
        #pragma unroll
        for (int ctl = 0; ctl < 8; ++ctl) {
            short8 bfrag = *(const short8*)(&Wl[ctl * 16 + q][(ks * 4 + quad) * 8]);
            acc[0][ctl] = __builtin_amdgcn_mfma_f32_16x16x32_bf16(a[ks][0], bfrag, acc[0][ctl], 0, 0, 0);
            acc[1][ctl] = __builtin_amdgcn_mfma_f32_16x16x32_bf16(a[ks][1], bfrag, acc[1][ctl], 0, 0, 0);
        }
    }

    // 4. LSTM epilogue, all 4 gates in-register per (b, r)
    float bo[2][4];
    #pragma unroll
    for (int rh = 0; rh < 2; ++rh)
        #pragma unroll
        for (int g = 0; g < 4; ++g)
            bo[rh][g] = b_out[g * 64 + (h * 2 + rh) * 16 + q];

    #pragma unroll
    for (int rt = 0; rt < 2; ++rt) {
        #pragma unroll
        for (int v = 0; v < 4; ++v) {
            const int b = w * 32 + rt * 16 + quad * 4 + v;
            const size_t base = (size_t)b * HID + n * RU;
            #pragma unroll
            for (int rh = 0; rh < 2; ++rh) {
                // reference: val = sigmoid(matmul) + b_out, THEN gate activations
                float vi = fsig(acc[rt][rh * 4 + 0][v]) + bo[rh][0];
                float vf = fsig(acc[rt][rh * 4 + 1][v]) + bo[rh][1];
                float vg = fsig(acc[rt][rh * 4 + 2][v]) + bo[rh][2];
                float vo = fsig(acc[rt][rh * 4 + 3][v]) + bo[rh][3];
                float it = fsig(vi), ft = fsig(vf);
                float gt = ftanh(vg), ot = fsig(vo);
                const size_t idx = base + (h * 2 + rh) * 16 + q;
                float cc = cx[idx] * ft + it * gt;
                out[idx] = ot * ftanh(cc);               // hy
                out[(size_t)BATCH * HID + idx] = cc;     // cy
            }
        }
    }
}

extern "C" void kernel_launch(void* const* d_in, const int* in_sizes, int n_in,
                              void* d_out, int out_size, void* d_ws, size_t ws_size,
                              hipStream_t stream) {
    const float* inputs = (const float*)d_in[0];
    const float* hx     = (const float*)d_in[1];
    const float* cx     = (const float*)d_in[2];
    const float* memory = (const float*)d_in[3];
    const float* w1     = (const float*)d_in[4];
    const float* b1     = (const float*)d_in[5];
    const float* w2     = (const float*)d_in[6];
    const float* b2     = (const float*)d_in[7];
    const float* w3     = (const float*)d_in[8];
    const float* b3     = (const float*)d_in[9];
    const float* b_out  = (const float*)d_in[10];
    float* out = (float*)d_out;

    unsigned short* W_ws = (unsigned short*)d_ws;   // needs 512*53248 B = 27.3 MB

    wgen_kernel<<<NNODE, 256, 0, stream>>>(memory, w1, b1, w2, b2, w3, b3, W_ws);
    gemm_kernel<<<NNODE * 2, 256, 0, stream>>>(inputs, hx, cx, b_out, W_ws, out);
}

// Round 4
// 136.725 us; speedup vs baseline: 1.3242x; 1.0199x over previous
//
#include <hip/hip_runtime.h>
#include <math.h>

#define BATCH 128
#define NNODE 512
#define RU 64
#define MEM_DIM 16
#define BOT_DIM 4
#define IN_SZ 66
#define OUT_SZ 256
#define HID (NNODE*RU)          // 32768
#define W3_ROW 16896            // IN_SZ*OUT_SZ
#define COL_SHORTS 104          // 13 x 8 bf16 per column in W_ws
#define NODE_W_SHORTS (256*COL_SHORTS)   // 26624 shorts per node
#define HALF_W_SHORTS (128*COL_SHORTS)
#define W3S_STRIDE 84           // dwords; 336B = 21*16 (aligned), 20*cl mod 32 -> 8 bank-starts
#define B3S_STRIDE 72           // dwords; 288B = 18*16 (aligned)

typedef __attribute__((ext_vector_type(8))) short short8;
typedef __attribute__((ext_vector_type(4))) float float4v;

__device__ __forceinline__ unsigned short f2bf(float f) {
    unsigned int u = __float_as_uint(f);
    unsigned int r = (u + 0x7FFFu + ((u >> 16) & 1u)) >> 16;
    return (unsigned short)r;
}
__device__ __forceinline__ float fsig(float x) {
    return __builtin_amdgcn_rcpf(1.0f + __expf(-x));
}
__device__ __forceinline__ float ftanh(float x) {
    return 1.0f - 2.0f * __builtin_amdgcn_rcpf(1.0f + __expf(2.0f * x));
}
// column slot c (global) -> output index o. c = ct*16+q, o = (ct&3)*64+(ct>>2)*16+q
__device__ __forceinline__ int omap(int cg, int cl) {
    int ct = cg * 2 + (cl >> 4);
    return (ct & 3) * 64 + ((ct >> 2) << 4) + (cl & 15);
}

// ---------------- Kernel 1: streaming W materialization ----------------
// Block = (cg: 32-col group, ng: 8-node group). w3/b3 slice staged ONCE in LDS
// (slot-permuted so chunk reads are aligned b128), then 8 nodes stream out.
__global__ __launch_bounds__(256) void wgen_kernel(
    const float* __restrict__ memory, const float* __restrict__ w1,
    const float* __restrict__ b1,     const float* __restrict__ w2,
    const float* __restrict__ b2,     const float* __restrict__ w3,
    const float* __restrict__ b3,     unsigned short* __restrict__ W_ws)
{
    __shared__ alignas(16) float w3s[4][32][W3S_STRIDE];  // 43008 B
    __shared__ alignas(16) float b3s[32][B3S_STRIDE];     //  9216 B
    __shared__ float mem1s[8][MEM_DIM];                   //   512 B
    __shared__ float m2s[8][BOT_DIM];                     //   128 B

    const int tid = threadIdx.x;
    const int cg  = (int)blockIdx.x & 7;
    const int ng  = (int)blockIdx.x >> 3;

    // ---- stage w3 slice, slot-permuted: s<64 -> i=s+2; s=64,65 -> i=0,1; s>=66 -> 0
    for (int e = tid; e < 4 * 32 * 72; e += 256) {
        int cl = e & 31;
        int r  = e >> 5;          // k*72 + s
        int k  = r / 72;
        int s  = r - k * 72;
        float v = 0.f;
        if (s < 66) {
            int i = (s < 64) ? s + 2 : s - 64;
            v = w3[k * W3_ROW + i * OUT_SZ + omap(cg, cl)];
        }
        w3s[k][cl][s] = v;
    }
    for (int e = tid; e < 32 * 72; e += 256) {
        int cl = e & 31;
        int s  = e >> 5;
        float v = 0.f;
        if (s < 66) {
            int i = (s < 64) ? s + 2 : s - 64;
            v = b3[i * OUT_SZ + omap(cg, cl)];
        }
        b3s[cl][s] = v;
    }

    // ---- hypernet for this block's 8 nodes (once, not per-thread) ----
    if (tid < 128) {
        int nn = tid >> 4, t = tid & 15;
        int n  = ng * 8 + nn;
        float s = b1[t];
        #pragma unroll
        for (int j = 0; j < MEM_DIM; ++j)
            s += memory[n * MEM_DIM + j] * w1[j * MEM_DIM + t];
        mem1s[nn][t] = ftanh(s);
    }
    __syncthreads();
    if (tid < 32) {
        int nn = tid >> 2, t = tid & 3;
        float s = b2[t];
        #pragma unroll
        for (int j = 0; j < MEM_DIM; ++j)
            s += mem1s[nn][j] * w2[j * BOT_DIM + t];
        m2s[nn][t] = ftanh(s);
    }
    __syncthreads();

    // ---- stream out: 4 node-pairs; thread t owns chunk (nn2, cl, sc) ----
    // chunk address = n*26624 + cg*3328 + cl*104 + sc*8: consecutive t -> contiguous 16B
    for (int p = 0; p < 4; ++p) {
        const int n0 = ng * 8 + p * 2;
        float ma[4], mb[4];
        #pragma unroll
        for (int k = 0; k < 4; ++k) { ma[k] = m2s[p * 2][k]; mb[k] = m2s[p * 2 + 1][k]; }

        for (int t = tid; t < 832; t += 256) {
            int nn2 = t >= 416;
            int rem = nn2 ? t - 416 : t;
            int cl  = rem / 13;
            int sc  = rem - cl * 13;
            short8 ov = {0, 0, 0, 0, 0, 0, 0, 0};
            if (sc < 9) {   // sc>=9 -> s>=72, all pad zeros
                const int s0 = sc * 8;
                float4v v0 = *(const float4v*)&b3s[cl][s0];
                float4v v1 = *(const float4v*)&b3s[cl][s0 + 4];
                #pragma unroll
                for (int k = 0; k < 4; ++k) {
                    float mk = nn2 ? mb[k] : ma[k];
                    float4v w0 = *(const float4v*)&w3s[k][cl][s0];
                    float4v w1v = *(const float4v*)&w3s[k][cl][s0 + 4];
                    v0 += mk * w0;
                    v1 += mk * w1v;
                }
                ov[0] = (short)f2bf(v0[0]); ov[1] = (short)f2bf(v0[1]);
                ov[2] = (short)f2bf(v0[2]); ov[3] = (short)f2bf(v0[3]);
                ov[4] = (short)f2bf(v1[0]); ov[5] = (short)f2bf(v1[1]);
                ov[6] = (short)f2bf(v1[2]); ov[7] = (short)f2bf(v1[3]);
            }
            unsigned short* dst = W_ws + (size_t)(n0 + nn2) * NODE_W_SHORTS
                                + cg * 3328 + cl * COL_SHORTS + sc * 8;
            *(short8*)dst = ov;
        }
    }
}

// ---------------- Kernel 2: MFMA GEMM + LSTM epilogue ----------------
__global__ __launch_bounds__(256, 3) void gemm_kernel(
    const float* __restrict__ inputs, const float* __restrict__ hx,
    const float* __restrict__ cx,     const float* __restrict__ b_out,
    const unsigned short* __restrict__ W_ws, float* __restrict__ out)
{
    __shared__ unsigned short Wl[128][COL_SHORTS];   // 26624 B
    const int tid  = threadIdx.x;
    const int n    = (int)blockIdx.x >> 1;
    const int h    = (int)blockIdx.x & 1;
    const int w    = tid >> 6;
    const int lane = tid & 63;
    const int q    = lane & 15;
    const int quad = lane >> 4;

    // 1. async DMA W half-tile
    const unsigned short* gW = W_ws + (size_t)n * NODE_W_SHORTS + h * HALF_W_SHORTS;
    for (int t = w; t < 26; t += 4) {
        __builtin_amdgcn_global_load_lds(
            (__attribute__((address_space(1))) void*)(gW + t * 512 + lane * 8),
            (__attribute__((address_space(3))) void*)(&Wl[0][0] + t * 512),
            16, 0, 0);
    }

    // 2. A fragments + cx + b_out from global while DMA is in flight
    short8 a[3][2];
    #pragma unroll
    for (int rt = 0; rt < 2; ++rt) {
        const int row = w * 32 + rt * 16 + q;
        const float* hrow = hx + (size_t)row * HID + n * RU + quad * 8;
        #pragma unroll
        for (int ks = 0; ks < 2; ++ks) {
            float4v f0 = *(const float4v*)(hrow + ks * 32);
            float4v f1 = *(const float4v*)(hrow + ks * 32 + 4);
            short8 t;
            t[0] = (short)f2bf(f0[0]); t[1] = (short)f2bf(f0[1]);
            t[2] = (short)f2bf(f0[2]); t[3] = (short)f2bf(f0[3]);
            t[4] = (short)f2bf(f1[0]); t[5] = (short)f2bf(f1[1]);
            t[6] = (short)f2bf(f1[2]); t[7] = (short)f2bf(f1[3]);
            a[ks][rt] = t;
        }
        short8 t2 = {0, 0, 0, 0, 0, 0, 0, 0};
        if (quad == 0) {
            const float* ip = inputs + (size_t)row * (NNODE * 2) + n * 2;
            t2[0] = (short)f2bf(ip[0]);
            t2[1] = (short)f2bf(ip[1]);
        }
        a[2][rt] = t2;
    }

    float cxr[2][4][2];
    #pragma unroll
    for (int rt = 0; rt < 2; ++rt)
        #pragma unroll
        for (int v = 0; v < 4; ++v) {
            const int b = w * 32 + rt * 16 + quad * 4 + v;
            #pragma unroll
            for (int rh = 0; rh < 2; ++rh)
                cxr[rt][v][rh] = cx[(size_t)b * HID + n * RU + (h * 2 + rh) * 16 + q];
        }

    float bo[2][4];
    #pragma unroll
    for (int rh = 0; rh < 2; ++rh)
        #pragma unroll
        for (int g = 0; g < 4; ++g)
            bo[rh][g] = b_out[g * 64 + (h * 2 + rh) * 16 + q];

    float4v acc[2][8];
    #pragma unroll
    for (int rt = 0; rt < 2; ++rt)
        #pragma unroll
        for (int ctl = 0; ctl < 8; ++ctl)
            acc[rt][ctl] = (float4v){0.f, 0.f, 0.f, 0.f};

    __syncthreads();   // drains DMA + barrier

    // 3. K-loop
    #pragma unroll
    for (int ks = 0; ks < 3; ++ks) {
        #pragma unroll
        for (int ctl = 0; ctl < 8; ++ctl) {
            short8 bfrag = *(const short8*)(&Wl[ctl * 16 + q][(ks * 4 + quad) * 8]);
            acc[0][ctl] = __builtin_amdgcn_mfma_f32_16x16x32_bf16(a[ks][0], bfrag, acc[0][ctl], 0, 0, 0);
            acc[1][ctl] = __builtin_amdgcn_mfma_f32_16x16x32_bf16(a[ks][1], bfrag, acc[1][ctl], 0, 0, 0);
        }
    }

    // 4. LSTM epilogue
    #pragma unroll
    for (int rt = 0; rt < 2; ++rt) {
        #pragma unroll
        for (int v = 0; v < 4; ++v) {
            const int b = w * 32 + rt * 16 + quad * 4 + v;
            const size_t base = (size_t)b * HID + n * RU;
            #pragma unroll
            for (int rh = 0; rh < 2; ++rh) {
                // reference: val = sigmoid(matmul) + b_out, THEN gate activations
                float vi = fsig(acc[rt][rh * 4 + 0][v]) + bo[rh][0];
                float vf = fsig(acc[rt][rh * 4 + 1][v]) + bo[rh][1];
                float vg = fsig(acc[rt][rh * 4 + 2][v]) + bo[rh][2];
                float vo = fsig(acc[rt][rh * 4 + 3][v]) + bo[rh][3];
                float it = fsig(vi), ft = fsig(vf);
                float gt = ftanh(vg), ot = fsig(vo);
                const size_t idx = base + (h * 2 + rh) * 16 + q;
                float cc = cxr[rt][v][rh] * ft + it * gt;
                out[idx] = ot * ftanh(cc);               // hy
                out[(size_t)BATCH * HID + idx] = cc;     // cy
            }
        }
    }
}

extern "C" void kernel_launch(void* const* d_in, const int* in_sizes, int n_in,
                              void* d_out, int out_size, void* d_ws, size_t ws_size,
                              hipStream_t stream) {
    const float* inputs = (const float*)d_in[0];
    const float* hx     = (const float*)d_in[1];
    const float* cx     = (const float*)d_in[2];
    const float* memory = (const float*)d_in[3];
    const float* w1     = (const float*)d_in[4];
    const float* b1     = (const float*)d_in[5];
    const float* w2     = (const float*)d_in[6];
    const float* b2     = (const float*)d_in[7];
    const float* w3     = (const float*)d_in[8];
    const float* b3     = (const float*)d_in[9];
    const float* b_out  = (const float*)d_in[10];
    float* out = (float*)d_out;

    unsigned short* W_ws = (unsigned short*)d_ws;   // 27.3 MB

    wgen_kernel<<<NNODE, 256, 0, stream>>>(memory, w1, b1, w2, b2, w3, b3, W_ws);
    gemm_kernel<<<NNODE * 2, 256, 0, stream>>>(inputs, hx, cx, b_out, W_ws, out);
}